// Round 1
// 450.278 us; speedup vs baseline: 1.3337x; 1.3337x over previous
//
#include <hip/hip_runtime.h>
#include <stdint.h>

#define BATCH 8192
#define IN 4096
#define OUT 4096
#define EPS 1e-4f
#define RCHUNK 128
#define NCHUNKS (BATCH / RCHUNK)   // 64

typedef int v4i __attribute__((ext_vector_type(4)));

#define AS1(p) ((const __attribute__((address_space(1))) void*)(p))
#define AS3(p) ((__attribute__((address_space(3))) void*)(p))

// ---------------- Kernel 1: partial column sums (S1, S2) ----------------
__global__ __launch_bounds__(256) void colstat_partial(
    const float* __restrict__ x, float* __restrict__ P1, float* __restrict__ P2) {
    int col = blockIdx.x * 256 + threadIdx.x;
    int r0 = blockIdx.y * RCHUNK;
    float s1 = 0.f, s2 = 0.f;
    const float* p = x + (size_t)r0 * IN + col;
    for (int r = 0; r < RCHUNK; ++r) {
        float v = p[(size_t)r * IN];
        s1 += v;
        s2 += v * v;
    }
    P1[blockIdx.y * IN + col] = s1;
    P2[blockIdx.y * IN + col] = s2;
}

// ---------------- Kernel 2: finalize mu, a = rstd*gamma ----------------
__global__ __launch_bounds__(256) void colstat_final(
    const float* __restrict__ P1, const float* __restrict__ P2,
    const float* __restrict__ gamma, float* __restrict__ mu, float* __restrict__ aArr) {
    int col = blockIdx.x * 256 + threadIdx.x;
    double s1 = 0.0, s2 = 0.0;
    for (int c = 0; c < NCHUNKS; ++c) {
        s1 += (double)P1[c * IN + col];
        s2 += (double)P2[c * IN + col];
    }
    double m = s1 / (double)BATCH;
    double var = s2 / (double)BATCH - m * m;
    float rstd = (float)(1.0 / sqrt(var + (double)EPS));
    mu[col] = (float)m;
    aArr[col] = rstd * gamma[col];
}

// ---------------- Kernel 3: binarize x -> {0,1} bytes + row popcount ----------------
__global__ __launch_bounds__(256) void binx8(
    const float* __restrict__ x, const float* __restrict__ mu,
    const float* __restrict__ aArr, const float* __restrict__ beta,
    uint8_t* __restrict__ x01, int* __restrict__ px) {
    __shared__ int red[4];
    int r = blockIdx.x;
    int tid = threadIdx.x;
    int lane = tid & 63;
    int wv = tid >> 6;
    const float4* row = (const float4*)(x + (size_t)r * IN);
    const float4* m4 = (const float4*)mu;
    const float4* a4 = (const float4*)aArr;
    const float4* b4 = (const float4*)beta;
    uchar4* o4 = (uchar4*)(x01 + (size_t)r * IN);
    int cnt = 0;
#pragma unroll
    for (int it = 0; it < IN / 1024; ++it) {   // 4 iters
        int q = it * 256 + tid;                // float4 index
        float4 v = row[q];
        float4 m = m4[q];
        float4 a = a4[q];
        float4 b = b4[q];
        uchar4 ob;
        ob.x = (uint8_t)((v.x - m.x) * a.x + b.x > 0.f);
        ob.y = (uint8_t)((v.y - m.y) * a.y + b.y > 0.f);
        ob.z = (uint8_t)((v.z - m.z) * a.z + b.z > 0.f);
        ob.w = (uint8_t)((v.w - m.w) * a.w + b.w > 0.f);
        cnt += (int)ob.x + (int)ob.y + (int)ob.z + (int)ob.w;
        o4[q] = ob;
    }
    for (int off = 32; off > 0; off >>= 1) cnt += __shfl_down(cnt, off, 64);
    if (lane == 0) red[wv] = cnt;
    __syncthreads();
    if (tid == 0) px[r] = red[0] + red[1] + red[2] + red[3];
}

// ---------------- Kernel 4: binarize weight -> {0,1} bytes + scale + row popcount ----------------
__global__ __launch_bounds__(256) void binw8(
    const float* __restrict__ w, uint8_t* __restrict__ w01,
    float* __restrict__ scale, int* __restrict__ pw) {
    __shared__ double redd[4];
    __shared__ int redi[4];
    __shared__ double bcast;
    int o = blockIdx.x;
    int tid = threadIdx.x;
    int lane = tid & 63;
    int wv = tid >> 6;
    const float4* row = (const float4*)(w + (size_t)o * IN);
    uchar4* o4 = (uchar4*)(w01 + (size_t)o * IN);

    // pass 1: row mean
    float4 vs[4];
    float part = 0.f;
#pragma unroll
    for (int it = 0; it < 4; ++it) {
        vs[it] = row[it * 256 + tid];
        part += vs[it].x + vs[it].y + vs[it].z + vs[it].w;
    }
    double d = (double)part;
    for (int off = 32; off > 0; off >>= 1) d += __shfl_down(d, off, 64);
    if (lane == 0) redd[wv] = d;
    __syncthreads();
    if (tid == 0) bcast = (redd[0] + redd[1] + redd[2] + redd[3]) / (double)IN;
    __syncthreads();
    float mean = (float)bcast;

    // pass 2: sign bits as bytes + L1 scale of clipped centered weights
    float absacc = 0.f;
    int cnt = 0;
#pragma unroll
    for (int it = 0; it < 4; ++it) {
        float4 v = vs[it];
        float wcx = v.x - mean, wcy = v.y - mean, wcz = v.z - mean, wcw = v.w - mean;
        uchar4 ob;
        ob.x = (uint8_t)(wcx > 0.f);
        ob.y = (uint8_t)(wcy > 0.f);
        ob.z = (uint8_t)(wcz > 0.f);
        ob.w = (uint8_t)(wcw > 0.f);
        cnt += (int)ob.x + (int)ob.y + (int)ob.z + (int)ob.w;
        absacc += fminf(fabsf(wcx), 1.0f) + fminf(fabsf(wcy), 1.0f) +
                  fminf(fabsf(wcz), 1.0f) + fminf(fabsf(wcw), 1.0f);
        o4[it * 256 + tid] = ob;
    }
    double da = (double)absacc;
    for (int off = 32; off > 0; off >>= 1) da += __shfl_down(da, off, 64);
    for (int off = 32; off > 0; off >>= 1) cnt += __shfl_down(cnt, off, 64);
    if (lane == 0) { redd[wv] = da; redi[wv] = cnt; }
    __syncthreads();
    if (tid == 0) {
        scale[o] = (float)((redd[0] + redd[1] + redd[2] + redd[3]) / (double)IN);
        pw[o] = redi[0] + redi[1] + redi[2] + redi[3];
    }
}

// ---------------- Kernel 5: i8 MFMA GEMM on {0,1} bytes ----------------
// 128x128 tile, 4 waves in 2x2 grid, each wave 64x64 = 4x4 frags of 16x16,
// K-step 64 i8 (64 B/row, same byte geometry as the proven m97 bf16 config).
// dot_{+-1} = 4*acc - 2*px[r] - 2*pw[c] + IN
#define BM 128
#define BN 128
#define BKI 64
__global__ __launch_bounds__(256, 2) void bgemm_i8(
    const uint8_t* __restrict__ x01, const uint8_t* __restrict__ w01,
    const int* __restrict__ px, const int* __restrict__ pw,
    const float* __restrict__ scale, const float* __restrict__ bias,
    float* __restrict__ out) {
    __shared__ uint8_t As[BM * BKI];   // 8 KB
    __shared__ uint8_t Bs[BN * BKI];   // 8 KB

    int tid = threadIdx.x;
    int lane = tid & 63;
    int wave = tid >> 6;
    int rowBlk = blockIdx.y * BM;
    int colBlk = blockIdx.x * BN;
    int wm = (wave >> 1) * 64;   // wave row offset in tile
    int wn = (wave & 1) * 64;    // wave col offset in tile

    v4i acc[4][4];
#pragma unroll
    for (int i = 0; i < 4; ++i)
#pragma unroll
        for (int j = 0; j < 4; ++j) acc[i][j] = (v4i){0, 0, 0, 0};

    const uint8_t* ag = x01 + (size_t)rowBlk * IN;
    const uint8_t* bg = w01 + (size_t)colBlk * IN;

    int lrow = lane & 15;
    int lk = (lane >> 4) * 16;

    for (int kc = 0; kc < IN / BKI; ++kc) {   // 64 K-steps
        // stage A+B tiles: 16 KB total, 4 x global_load_lds_dwordx4 per thread
#pragma unroll
        for (int it = 0; it < 2; ++it) {
            int idx = tid + it * 256;          // 0..511
            int r = idx >> 2;                  // tile row 0..127
            int ch = idx & 3;                  // 16B chunk within 64B row
            __builtin_amdgcn_global_load_lds(
                AS1(ag + (size_t)r * IN + kc * BKI + ch * 16),
                AS3(As + idx * 16), 16, 0, 0);
            __builtin_amdgcn_global_load_lds(
                AS1(bg + (size_t)r * IN + kc * BKI + ch * 16),
                AS3(Bs + idx * 16), 16, 0, 0);
        }
        __syncthreads();

        v4i af[4], bf[4];
#pragma unroll
        for (int i = 0; i < 4; ++i)
            af[i] = *(const v4i*)(As + (wm + i * 16 + lrow) * BKI + lk);
#pragma unroll
        for (int j = 0; j < 4; ++j)
            bf[j] = *(const v4i*)(Bs + (wn + j * 16 + lrow) * BKI + lk);
#pragma unroll
        for (int i = 0; i < 4; ++i)
#pragma unroll
            for (int j = 0; j < 4; ++j)
                acc[i][j] = __builtin_amdgcn_mfma_i32_16x16x64_i8(af[i], bf[j], acc[i][j], 0, 0, 0);
        __syncthreads();
    }

    // epilogue: C/D layout col=lane&15, row=(lane>>4)*4+reg
    int crow0 = (lane >> 4) * 4;
    int ccol = lane & 15;
#pragma unroll
    for (int i = 0; i < 4; ++i) {
        int rbase = rowBlk + wm + i * 16 + crow0;
        int pxr[4];
#pragma unroll
        for (int rg = 0; rg < 4; ++rg) pxr[rg] = px[rbase + rg];
#pragma unroll
        for (int j = 0; j < 4; ++j) {
            int cb = colBlk + wn + j * 16 + ccol;
            float sc = scale[cb];
            float bs = bias[cb];
            int pwc = pw[cb];
#pragma unroll
            for (int rg = 0; rg < 4; ++rg) {
                int dot = 4 * acc[i][j][rg] - 2 * pxr[rg] - 2 * pwc + IN;
                float y = ((float)dot + bs) * sc;
                out[(size_t)(rbase + rg) * OUT + cb] = y > 0.f ? y : 0.f;
            }
        }
    }
}

extern "C" void kernel_launch(void* const* d_in, const int* in_sizes, int n_in,
                              void* d_out, int out_size, void* d_ws, size_t ws_size,
                              hipStream_t stream) {
    const float* x = (const float*)d_in[0];
    const float* gamma = (const float*)d_in[1];
    const float* beta = (const float*)d_in[2];
    const float* weight = (const float*)d_in[3];
    const float* bias = (const float*)d_in[4];
    float* out = (float*)d_out;

    char* w = (char*)d_ws;
    float* mu = (float*)(w);                    // 16 KB
    float* aArr = (float*)(w + 16384);          // 16 KB
    float* scale = (float*)(w + 32768);         // 16 KB
    int* px = (int*)(w + 49152);                // 32 KB
    int* pw = (int*)(w + 81920);                // 16 KB
    float* P1 = (float*)(w + (1 << 20));        // 1 MB
    float* P2 = (float*)(w + (2 << 20));        // 1 MB
    uint8_t* x01 = (uint8_t*)(w + (4 << 20));   // 32 MB
    uint8_t* w01 = (uint8_t*)(w + (36 << 20));  // 16 MB  (total 52 MB)

    colstat_partial<<<dim3(IN / 256, NCHUNKS), 256, 0, stream>>>(x, P1, P2);
    colstat_final<<<dim3(IN / 256), 256, 0, stream>>>(P1, P2, gamma, mu, aArr);
    binx8<<<dim3(BATCH), 256, 0, stream>>>(x, mu, aArr, beta, x01, px);
    binw8<<<dim3(OUT), 256, 0, stream>>>(weight, w01, scale, pw);
    bgemm_i8<<<dim3(OUT / BN, BATCH / BM), 256, 0, stream>>>(x01, w01, px, pw, scale, bias, out);
}

// Round 2
// 412.237 us; speedup vs baseline: 1.4567x; 1.0923x over previous
//
#include <hip/hip_runtime.h>
#include <stdint.h>

#define BATCH 8192
#define IN 4096
#define OUT 4096
#define EPS 1e-4f
#define RCHUNK 128
#define NCHUNKS (BATCH / RCHUNK)   // 64

typedef int v4i __attribute__((ext_vector_type(4)));
typedef unsigned char u8;

#define AS1(p) ((const __attribute__((address_space(1))) void*)(p))
#define AS3(p) ((__attribute__((address_space(3))) void*)(p))

// ---------------- Kernel 1: partial column sums (S1, S2), float4 ----------------
__global__ __launch_bounds__(256) void colstat_partial(
    const float* __restrict__ x, float* __restrict__ P1, float* __restrict__ P2) {
    int c4 = blockIdx.x * 256 + threadIdx.x;   // float4 column index 0..1023
    int r0 = blockIdx.y * RCHUNK;
    float4 s1 = {0.f, 0.f, 0.f, 0.f}, s2 = {0.f, 0.f, 0.f, 0.f};
    const float4* p = (const float4*)x + (size_t)r0 * (IN / 4) + c4;
    for (int r = 0; r < RCHUNK; ++r) {
        float4 v = p[(size_t)r * (IN / 4)];
        s1.x += v.x; s1.y += v.y; s1.z += v.z; s1.w += v.w;
        s2.x += v.x * v.x; s2.y += v.y * v.y; s2.z += v.z * v.z; s2.w += v.w * v.w;
    }
    ((float4*)P1)[blockIdx.y * (IN / 4) + c4] = s1;
    ((float4*)P2)[blockIdx.y * (IN / 4) + c4] = s2;
}

// ---------------- Kernel 2: finalize mu, a = rstd*gamma ----------------
__global__ __launch_bounds__(256) void colstat_final(
    const float* __restrict__ P1, const float* __restrict__ P2,
    const float* __restrict__ gamma, float* __restrict__ mu, float* __restrict__ aArr) {
    int col = blockIdx.x * 256 + threadIdx.x;
    double s1 = 0.0, s2 = 0.0;
    for (int c = 0; c < NCHUNKS; ++c) {
        s1 += (double)P1[c * IN + col];
        s2 += (double)P2[c * IN + col];
    }
    double m = s1 / (double)BATCH;
    double var = s2 / (double)BATCH - m * m;
    float rstd = (float)(1.0 / sqrt(var + (double)EPS));
    mu[col] = (float)m;
    aArr[col] = rstd * gamma[col];
}

// ---------------- Kernel 3: binarize x -> {0,1} bytes + row popcount ----------------
__global__ __launch_bounds__(256) void binx8(
    const float* __restrict__ x, const float* __restrict__ mu,
    const float* __restrict__ aArr, const float* __restrict__ beta,
    u8* __restrict__ x01, int* __restrict__ px) {
    __shared__ int red[4];
    int r = blockIdx.x;
    int tid = threadIdx.x;
    int lane = tid & 63;
    int wv = tid >> 6;
    const float4* row = (const float4*)(x + (size_t)r * IN);
    const float4* m4 = (const float4*)mu;
    const float4* a4 = (const float4*)aArr;
    const float4* b4 = (const float4*)beta;
    uchar4* o4 = (uchar4*)(x01 + (size_t)r * IN);
    int cnt = 0;
#pragma unroll
    for (int it = 0; it < IN / 1024; ++it) {   // 4 iters
        int q = it * 256 + tid;
        float4 v = row[q];
        float4 m = m4[q];
        float4 a = a4[q];
        float4 b = b4[q];
        uchar4 ob;
        ob.x = (u8)((v.x - m.x) * a.x + b.x > 0.f);
        ob.y = (u8)((v.y - m.y) * a.y + b.y > 0.f);
        ob.z = (u8)((v.z - m.z) * a.z + b.z > 0.f);
        ob.w = (u8)((v.w - m.w) * a.w + b.w > 0.f);
        cnt += (int)ob.x + (int)ob.y + (int)ob.z + (int)ob.w;
        o4[q] = ob;
    }
    for (int off = 32; off > 0; off >>= 1) cnt += __shfl_down(cnt, off, 64);
    if (lane == 0) red[wv] = cnt;
    __syncthreads();
    if (tid == 0) px[r] = red[0] + red[1] + red[2] + red[3];
}

// ---------------- Kernel 4: binarize weight -> {0,1} bytes + scale + popcount ----------------
__global__ __launch_bounds__(256) void binw8(
    const float* __restrict__ w, u8* __restrict__ w01,
    float* __restrict__ scale, int* __restrict__ pw) {
    __shared__ double redd[4];
    __shared__ int redi[4];
    __shared__ double bcast;
    int o = blockIdx.x;
    int tid = threadIdx.x;
    int lane = tid & 63;
    int wv = tid >> 6;
    const float4* row = (const float4*)(w + (size_t)o * IN);
    uchar4* o4 = (uchar4*)(w01 + (size_t)o * IN);

    float4 vs[4];
    float part = 0.f;
#pragma unroll
    for (int it = 0; it < 4; ++it) {
        vs[it] = row[it * 256 + tid];
        part += vs[it].x + vs[it].y + vs[it].z + vs[it].w;
    }
    double d = (double)part;
    for (int off = 32; off > 0; off >>= 1) d += __shfl_down(d, off, 64);
    if (lane == 0) redd[wv] = d;
    __syncthreads();
    if (tid == 0) bcast = (redd[0] + redd[1] + redd[2] + redd[3]) / (double)IN;
    __syncthreads();
    float mean = (float)bcast;

    float absacc = 0.f;
    int cnt = 0;
#pragma unroll
    for (int it = 0; it < 4; ++it) {
        float4 v = vs[it];
        float wcx = v.x - mean, wcy = v.y - mean, wcz = v.z - mean, wcw = v.w - mean;
        uchar4 ob;
        ob.x = (u8)(wcx > 0.f);
        ob.y = (u8)(wcy > 0.f);
        ob.z = (u8)(wcz > 0.f);
        ob.w = (u8)(wcw > 0.f);
        cnt += (int)ob.x + (int)ob.y + (int)ob.z + (int)ob.w;
        absacc += fminf(fabsf(wcx), 1.0f) + fminf(fabsf(wcy), 1.0f) +
                  fminf(fabsf(wcz), 1.0f) + fminf(fabsf(wcw), 1.0f);
        o4[it * 256 + tid] = ob;
    }
    double da = (double)absacc;
    for (int off = 32; off > 0; off >>= 1) da += __shfl_down(da, off, 64);
    for (int off = 32; off > 0; off >>= 1) cnt += __shfl_down(cnt, off, 64);
    if (lane == 0) { redd[wv] = da; redi[wv] = cnt; }
    __syncthreads();
    if (tid == 0) {
        scale[o] = (float)((redd[0] + redd[1] + redd[2] + redd[3]) / (double)IN);
        pw[o] = redi[0] + redi[1] + redi[2] + redi[3];
    }
}

// ---------------- Kernel 5: i8 MFMA GEMM, 256x256 tile, 8-phase pipeline ----------------
// 8 waves (2M x 4N), per-wave 128x64 output = 8x4 frags of 16x16, BK=128 bytes.
// LDS 128 KiB: 2 bufs x (A 32K + B 32K). Even K-tiles -> buf0, odd -> buf1.
// Stage units = 64 rows x 128 B (1 global_load_lds x16B per thread).
// T2 swizzle: LDS slot = lin_slot ^ (row&7); applied on global SOURCE for staging
// (LDS dest must stay linear for global_load_lds) and on ds_read addresses.
// dot_{+-1} = 4*acc - 2*px[r] - 2*pw[c] + IN
#define BKB 128
#define NKT (IN / BKB)     // 32
#define NIT (NKT / 2)      // 16

#define STG_A(t, q, p) __builtin_amdgcn_global_load_lds( \
    AS1(ag + (size_t)((q)*64 + slr) * IN + (t)*BKB + sswz), \
    AS3(lds + (p)*65536 + (q)*8192 + sdst), 16, 0, 0)
#define STG_B(t, q, p) __builtin_amdgcn_global_load_lds( \
    AS1(bg + (size_t)((q)*64 + slr) * IN + (t)*BKB + sswz), \
    AS3(lds + (p)*65536 + 32768 + (q)*8192 + sdst), 16, 0, 0)

#define LOADA(p, rh) do { \
    _Pragma("unroll") for (int i_ = 0; i_ < 4; ++i_) \
    _Pragma("unroll") for (int k_ = 0; k_ < 2; ++k_) \
        af[i_][k_] = *(const v4i*)(lds + (p)*65536 + aBase + (rh)*8192 + i_*2048 + swk[k_]); \
} while (0)
#define LOADB(p, ch) do { \
    _Pragma("unroll") for (int j_ = 0; j_ < 2; ++j_) \
    _Pragma("unroll") for (int k_ = 0; k_ < 2; ++k_) \
        bf[j_][k_] = *(const v4i*)(lds + (p)*65536 + bBase + (ch)*4096 + j_*2048 + swk[k_]); \
} while (0)
#define MMA(rh, ch) do { \
    __builtin_amdgcn_s_setprio(1); \
    _Pragma("unroll") for (int i_ = 0; i_ < 4; ++i_) \
    _Pragma("unroll") for (int j_ = 0; j_ < 2; ++j_) \
    _Pragma("unroll") for (int k_ = 0; k_ < 2; ++k_) \
        acc[(rh)*4 + i_][(ch)*2 + j_] = __builtin_amdgcn_mfma_i32_16x16x64_i8( \
            af[i_][k_], bf[j_][k_], acc[(rh)*4 + i_][(ch)*2 + j_], 0, 0, 0); \
    __builtin_amdgcn_s_setprio(0); \
} while (0)
#define BAR() asm volatile("s_barrier" ::: "memory")
#define VM(n) asm volatile("s_waitcnt vmcnt(" #n ")" ::: "memory")

__global__ __launch_bounds__(512, 2) void bgemm_i8(
    const u8* __restrict__ x01, const u8* __restrict__ w01,
    const int* __restrict__ px, const int* __restrict__ pw,
    const float* __restrict__ scale, const float* __restrict__ bias,
    float* __restrict__ out) {
    __shared__ u8 lds[131072];

    int tid = threadIdx.x;
    int lane = tid & 63;
    int wave = tid >> 6;          // 0..7
    int wm = wave >> 2;           // 0..1  (row half)
    int wn = wave & 3;            // 0..3  (col quarter)

    // XCD-aware block swizzle (512 blocks, 512%8==0 -> bijective)
    int lin = blockIdx.y * (OUT / 256) + blockIdx.x;   // 0..511
    int swz = (lin & 7) * 64 + (lin >> 3);
    int colBlk = (swz & 15) * 256;
    int rowBlk = (swz >> 4) * 256;

    const u8* ag = x01 + (size_t)rowBlk * IN;
    const u8* bg = w01 + (size_t)colBlk * IN;

    // staging thread constants (linear LDS dest, inverse-swizzled global src)
    int slr = tid >> 3;                 // row within 64-row unit
    int ss = tid & 7;                   // 16B slot
    int sswz = (ss ^ (slr & 7)) * 16;   // swizzled source byte offset
    int sdst = slr * 128 + ss * 16;     // linear LDS byte offset within unit

    // ds_read thread constants
    int lrow = lane & 15;
    int lhi = lane >> 4;
    int llo = lane & 7;
    int swk[2] = { ((lhi) ^ llo) * 16, ((4 + lhi) ^ llo) * 16 };
    int aBase = (wm * 128 + lrow) * 128;
    int bBase = 32768 + (wn * 64 + lrow) * 128;

    v4i acc[8][4];
#pragma unroll
    for (int i = 0; i < 8; ++i)
#pragma unroll
        for (int j = 0; j < 4; ++j) acc[i][j] = (v4i){0, 0, 0, 0};
    v4i af[4][2], bf[2][2];

    // ---- prologue: tile0 fully (8 units), tile1 QA0,QA2 ----
    STG_A(0, 0, 0); STG_A(0, 1, 0); STG_A(0, 2, 0); STG_A(0, 3, 0);
    STG_B(0, 0, 0); STG_B(0, 1, 0); STG_B(0, 2, 0); STG_B(0, 3, 0);
    STG_A(1, 0, 1); STG_A(1, 2, 1);
    VM(2);
    BAR();

    // ---- steady iterations j=0..NIT-2: compute E=2j (buf0), O=2j+1 (buf1) ----
    for (int j = 0; j < NIT - 1; ++j) {
        int O = 2 * j + 1, E2 = 2 * j + 2, O2 = 2 * j + 3;
        // P1: E quadrant (rh0,ch0)
        LOADA(0, 0); LOADB(0, 0);
        STG_B(O, 0, 1); STG_B(O, 1, 1);
        BAR(); MMA(0, 0); BAR();
        // P2: (rh0,ch1)
        LOADB(0, 1);
        STG_B(O, 2, 1); STG_B(O, 3, 1);
        BAR(); MMA(0, 1); VM(6); BAR();
        // P3: (rh1,ch0)
        LOADA(0, 1); LOADB(0, 0);
        STG_A(O, 1, 1); STG_A(O, 3, 1); STG_A(E2, 0, 0); STG_A(E2, 2, 0);
        BAR(); MMA(1, 0); BAR();
        // P4: (rh1,ch1)
        LOADB(0, 1);
        BAR(); MMA(1, 1); VM(4); BAR();
        // P5: O quadrant (rh0,ch0)
        LOADA(1, 0); LOADB(1, 0);
        STG_B(E2, 0, 0); STG_B(E2, 1, 0);
        BAR(); MMA(0, 0); BAR();
        // P6: (rh0,ch1)
        LOADB(1, 1);
        STG_B(E2, 2, 0); STG_B(E2, 3, 0);
        BAR(); MMA(0, 1); VM(4); BAR();
        // P7: (rh1,ch0)
        LOADA(1, 1); LOADB(1, 0);
        STG_A(E2, 1, 0); STG_A(E2, 3, 0);
        BAR(); MMA(1, 0); BAR();
        // P8: (rh1,ch1)
        LOADB(1, 1);
        STG_A(O2, 0, 1); STG_A(O2, 2, 1);
        BAR(); MMA(1, 1); VM(4); BAR();
    }

    // ---- peeled last iteration: E=30 (buf0), O=31 (buf1); no E2/O2 stages ----
    {
        int O = NKT - 1;   // 31
        // P1
        LOADA(0, 0); LOADB(0, 0);
        STG_B(O, 0, 1); STG_B(O, 1, 1);
        BAR(); MMA(0, 0); BAR();
        // P2
        LOADB(0, 1);
        STG_B(O, 2, 1); STG_B(O, 3, 1);
        BAR(); MMA(0, 1); VM(6); BAR();
        // P3
        LOADA(0, 1); LOADB(0, 0);
        STG_A(O, 1, 1); STG_A(O, 3, 1);
        BAR(); MMA(1, 0); BAR();
        // P4
        LOADB(0, 1);
        BAR(); MMA(1, 1); VM(2); BAR();
        // P5
        LOADA(1, 0); LOADB(1, 0);
        BAR(); MMA(0, 0); BAR();
        // P6
        LOADB(1, 1);
        BAR(); MMA(0, 1); VM(0); BAR();
        // P7
        LOADA(1, 1); LOADB(1, 0);
        BAR(); MMA(1, 0); BAR();
        // P8
        LOADB(1, 1);
        BAR(); MMA(1, 1); BAR();
    }

    // ---- epilogue ----
    int crow0 = lhi * 4;
    int ccol = lrow;
#pragma unroll
    for (int i = 0; i < 8; ++i) {
        int rbase = rowBlk + wm * 128 + i * 16 + crow0;
        int pxr[4];
#pragma unroll
        for (int rg = 0; rg < 4; ++rg) pxr[rg] = px[rbase + rg];
#pragma unroll
        for (int j = 0; j < 4; ++j) {
            int cb = colBlk + wn * 64 + j * 16 + ccol;
            float sc = scale[cb];
            float bs = bias[cb];
            int pwc = pw[cb];
#pragma unroll
            for (int rg = 0; rg < 4; ++rg) {
                int dot = 4 * acc[i][j][rg] - 2 * pxr[rg] - 2 * pwc + IN;
                float y = ((float)dot + bs) * sc;
                out[(size_t)(rbase + rg) * OUT + cb] = y > 0.f ? y : 0.f;
            }
        }
    }
}

extern "C" void kernel_launch(void* const* d_in, const int* in_sizes, int n_in,
                              void* d_out, int out_size, void* d_ws, size_t ws_size,
                              hipStream_t stream) {
    const float* x = (const float*)d_in[0];
    const float* gamma = (const float*)d_in[1];
    const float* beta = (const float*)d_in[2];
    const float* weight = (const float*)d_in[3];
    const float* bias = (const float*)d_in[4];
    float* out = (float*)d_out;

    char* w = (char*)d_ws;
    float* mu = (float*)(w);                    // 16 KB
    float* aArr = (float*)(w + 16384);          // 16 KB
    float* scale = (float*)(w + 32768);         // 16 KB
    int* px = (int*)(w + 49152);                // 32 KB
    int* pw = (int*)(w + 81920);                // 16 KB
    float* P1 = (float*)(w + (1 << 20));        // 1 MB
    float* P2 = (float*)(w + (2 << 20));        // 1 MB
    u8* x01 = (u8*)(w + (4 << 20));             // 32 MB
    u8* w01 = (u8*)(w + (36 << 20));            // 16 MB  (total 52 MB)

    colstat_partial<<<dim3(IN / 1024, NCHUNKS), 256, 0, stream>>>(x, P1, P2);
    colstat_final<<<dim3(IN / 256), 256, 0, stream>>>(P1, P2, gamma, mu, aArr);
    binx8<<<dim3(BATCH), 256, 0, stream>>>(x, mu, aArr, beta, x01, px);
    binw8<<<dim3(OUT), 256, 0, stream>>>(weight, w01, scale, pw);
    bgemm_i8<<<dim3(OUT / 256, BATCH / 256), 512, 0, stream>>>(x01, w01, px, pw, scale, bias, out);
}